// Round 5
// baseline (227.359 us; speedup 1.0000x reference)
//
#include <hip/hip_runtime.h>
#include <stdint.h>
#include <stddef.h>

// ---------------------------------------------------------------------------
// EinsumSelfAttention: LN(x + Attn(xWq^T+bq, xWk^T+bk, xWv^T+bv) Wo^T + bo)
// B=2 T=2048 D=1024 H=16 dk=64.  All matmuls via bf16 MFMA 32x32x16.
// Layouts: C/D (verified m74/m101): col=lane&31, row=(reg&3)+8*(reg>>2)+4*(lane>>5)
//          A/B frag: lane holds X[row/col=lane&31][k=(lane>>5)*8+j], j=0..7
// attn R9: S-TRANSPOSE trick. Compute S^T = K*Q^T (A=K, B=Q) so C has
// lane=q, regs=s. exp2+pack regs pairwise -> bf16x8 IS the B-operand of
// O^T = V^T * P^T, with V^T s-columns pre-permuted by
// sigma(j) = (j&3) + ((j>>2)&1)*8 + ((j>>3)&1)*4.
// => NO P LDS round-trip. li is a per-lane scalar.
// R10 (REVERTED): batched-QK + setprio 42.8->43.9us -> attn keeps R9 chain.
// R11: o_gemm 256->512 blocks (BM=64) for 2 blocks/CU.
// R12: v_trans fused into V-slice of qkv_gemm. R13: single shared 34 KB LDS
// buffer across gemm128 instantiations (fixed the 68 KB double-alloc; qkv
// 56.8->43.4us, occ 25.9%).
// R14 (this round): GEMM staging LDS re-laid out K-MAJOR [c][row][8]
// (chunk = c*ROWS+row, still lane-linear for global_load_lds; the global
// SOURCE address is what's permuted, m173 pattern). Old row-major [row][32]
// layout had 64B row stride and a 2-bit XOR -> 8 lanes per 16B slot on
// fragment reads = 9.57M SQ_LDS_BANK_CONFLICT (1168 cyc/CU/kt, the entire
// gap vs m97's equivalent structure). New layout: 16B row stride -> 4
// lanes/slot = b128 floor (same class as attn's K-read, which shows ~0).
// K-loops: async-LDS double buffer via global_load_lds, one barrier per tile.
// NO register-held tile data (R5: per-thread prefetch arrays -> scratch spill).
// Measured context: dur_us includes ~2x43us harness workspace-poison fills
// (268MB each, rocprof top-5) -> controllable kernel budget ~117us.
// ---------------------------------------------------------------------------

typedef __bf16 bf16_t;
typedef bf16_t bf16x8 __attribute__((ext_vector_type(8)));
typedef float f32x16 __attribute__((ext_vector_type(16)));
typedef float f32x2 __attribute__((ext_vector_type(2)));
typedef uint16_t u16x8 __attribute__((ext_vector_type(8)));

#define MFMA32(a, b, c) __builtin_amdgcn_mfma_f32_32x32x16_bf16((a), (b), (c), 0, 0, 0)

__device__ __forceinline__ uint16_t f2bf(float f) {
  __bf16 h = (__bf16)f;
  return *(uint16_t*)&h;
}

// async global->LDS, 16B per lane. LDS dest must be wave-uniform base + lane*16.
__device__ __forceinline__ void gload16(const void* g, void* l) {
  __builtin_amdgcn_global_load_lds((const __attribute__((address_space(1))) void*)g,
                                   (__attribute__((address_space(3))) void*)l,
                                   16, 0, 0);
}

// ------------------------------------------- fp32->bf16, all 5 tensors in one
__global__ __launch_bounds__(256) void cvt_all(
    const float* __restrict__ x, const float* __restrict__ wq,
    const float* __restrict__ wk, const float* __restrict__ wv,
    const float* __restrict__ wo, uint16_t* __restrict__ xb,
    uint16_t* __restrict__ wqb, uint16_t* __restrict__ wkb,
    uint16_t* __restrict__ wvb, uint16_t* __restrict__ wob) {
  const int gid = blockIdx.x * 256 + threadIdx.x;  // 2097152 float4 chunks
  const float* src; uint16_t* dst; int off;
  if (gid < 1048576) {
    src = x; dst = xb; off = gid;
  } else {
    const int t = gid - 1048576;
    off = t & 262143;
    switch (t >> 18) {
      case 0: src = wq; dst = wqb; break;
      case 1: src = wk; dst = wkb; break;
      case 2: src = wv; dst = wvb; break;
      default: src = wo; dst = wob; break;
    }
  }
  const float4 f = ((const float4*)src)[off];
  uint64_t p = (uint64_t)f2bf(f.x) | ((uint64_t)f2bf(f.y) << 16) |
               ((uint64_t)f2bf(f.z) << 32) | ((uint64_t)f2bf(f.w) << 48);
  ((uint64_t*)dst)[off] = p;
}

// ------------------------------------------------- 128x128 GEMM, C = A*Bt^T
// BK=32, LDS double-buffered, 256 threads = 4 waves (2x2 of 64x64, each wave
// 2x2 blocks of 32x32 MFMA), one barrier per k-tile.
// R14 LDS layout (per 128x32 tile, both A and B): K-MAJOR chunks,
//   chunk(c,row) = c*128 + row  (c = 16B k-group 0..3, row 0..127)
//   elem offset  = c*1024 + row*8
// Staged chunk ch (thread-linear) <- global A[(m0+row)][kt*32 + c*8 ..+8)
// with row = ch&127, c = ch>>7. Fragment read (uniform c, per-lane row) has
// 16B row stride -> 4 lanes per 16B slot = b128 bank floor (no conflicts).
// smem: caller-provided 17408-elem (34 KB) buffer (R13).
// MODE 0: bf16 row-major out.  MODE 2: V-path — epilogue transposes through
// LDS ([128 n][136 t], unioned with staging) and writes vbT (b,h,d,t) with
// the sigma s-permutation expected by attn's PV step.
template <int MODE>
__device__ __forceinline__ void gemm128(uint16_t* __restrict__ smem,
                                        const uint16_t* __restrict__ A,
                                        const uint16_t* __restrict__ Bt,
                                        const float* __restrict__ bias,
                                        float oscale,
                                        uint16_t* __restrict__ outb) {
  uint16_t* sAp = smem;          // [2][4096] elems, k-major chunks
  uint16_t* sBp = smem + 8192;   // [2][4096]
  const int tid = threadIdx.x;
  const int lane = tid & 63, w = tid >> 6;
  const int l31 = lane & 31, half = lane >> 5;
  const int m0 = blockIdx.y * 128, n0 = blockIdx.x * 128;
  const int wm = (w >> 1) * 64, wn = (w & 1) * 64;

  // chunk ch0 = tid -> (c = tid>>7, row = tid&127); ch1 = tid+256 -> c+2.
  const int srow = tid & 127, sc = tid >> 7;
  const uint16_t* a0 = A + (size_t)(m0 + srow) * 1024 + sc * 8;
  const uint16_t* a1 = a0 + 16;  // c+2 -> +16 elems
  const uint16_t* b0 = Bt + (size_t)(n0 + srow) * 1024 + sc * 8;
  const uint16_t* b1 = b0 + 16;

  gload16(a0, &sAp[tid * 8]);
  gload16(a1, &sAp[(tid + 256) * 8]);
  gload16(b0, &sBp[tid * 8]);
  gload16(b1, &sBp[(tid + 256) * 8]);

  f32x16 acc[2][2] = {};

  for (int kt = 0; kt < 32; ++kt) {
    __syncthreads();
    const int cur = kt & 1;
    if (kt < 31) {
      const int ko = (kt + 1) * 32;
      const int nxt = cur ^ 1;
      gload16(a0 + ko, &sAp[nxt * 4096 + tid * 8]);
      gload16(a1 + ko, &sAp[nxt * 4096 + (tid + 256) * 8]);
      gload16(b0 + ko, &sBp[nxt * 4096 + tid * 8]);
      gload16(b1 + ko, &sBp[nxt * 4096 + (tid + 256) * 8]);
    }
#pragma unroll
    for (int s = 0; s < 2; ++s) {
      const int c = s * 2 + half;
      bf16x8 af[2], bfr[2];
#pragma unroll
      for (int i = 0; i < 2; ++i) {
        const int arow = wm + i * 32 + l31;
        af[i] = *(const bf16x8*)&sAp[cur * 4096 + c * 1024 + arow * 8];
      }
#pragma unroll
      for (int j = 0; j < 2; ++j) {
        const int brow = wn + j * 32 + l31;
        bfr[j] = *(const bf16x8*)&sBp[cur * 4096 + c * 1024 + brow * 8];
      }
#pragma unroll
      for (int i = 0; i < 2; ++i)
#pragma unroll
        for (int j = 0; j < 2; ++j) acc[i][j] = MFMA32(af[i], bfr[j], acc[i][j]);
    }
  }

  if constexpr (MODE == 2) {
    // ---- fused v_trans epilogue ----
    __syncthreads();  // all waves done reading staging LDS
    uint16_t* vT = smem;  // [128 n][136 t]  (stride 272 B, 8B-aligned rows)
#pragma unroll
    for (int i = 0; i < 2; ++i)
#pragma unroll
      for (int j = 0; j < 2; ++j) {
        const int nl = wn + j * 32 + l31;
        const float bv = bias[n0 + nl];
#pragma unroll
        for (int g = 0; g < 4; ++g) {
          // regs 4g..4g+3 -> t = wm + i*32 + 8g + 4*half + (0..3)
          uint64_t pk = 0;
#pragma unroll
          for (int e = 0; e < 4; ++e)
            pk |= (uint64_t)f2bf(acc[i][j][g * 4 + e] + bv) << (16 * e);
          const int tl = wm + i * 32 + g * 8 + half * 4;
          *(uint64_t*)&vT[nl * 136 + tl] = pk;
        }
      }
    __syncthreads();
    // read phase: identical math to the old v_trans read loop.
    const int bb = m0 >> 11, tblk = m0 & 2047;
    const int h0 = n0 >> 6;
#pragma unroll
    for (int c = 0; c < 8; ++c) {
      const int idx = c * 256 + tid;
      const int nf = idx >> 4, t8 = (idx & 15) * 8;
      const int tb = t8 & ~15;            // 16-s block base
      const int add4 = (t8 & 8) ? 4 : 0;  // sigma for upper 8 slots
      u16x8 v;
#pragma unroll
      for (int e = 0; e < 8; ++e)
        v[e] = vT[nf * 136 + tb + ((e & 3) + ((e >> 2) << 3)) + add4];
      *(u16x8*)&outb[((size_t)(bb * 16 + h0 + (nf >> 6)) * 64 + (nf & 63)) * 2048 +
                     tblk + t8] = v;
    }
    return;
  }

#pragma unroll
  for (int i = 0; i < 2; ++i) {
#pragma unroll
    for (int j = 0; j < 2; ++j) {
      const int gn = n0 + wn + j * 32 + l31;
      const float bv = bias[gn];
#pragma unroll
      for (int reg = 0; reg < 16; ++reg) {
        const int gm = m0 + wm + i * 32 + (reg & 3) + 8 * (reg >> 2) + 4 * half;
        outb[(size_t)gm * 1024 + gn] = f2bf((acc[i][j][reg] + bv) * oscale);
      }
    }
  }
}

// ----------------------------------------- 64x128 GEMM variant for o_gemm.
// BM=64 BN=128 -> 512 blocks, 2 blocks/CU (24 KB LDS), 8 waves/CU.
// R14: same k-major LDS chunk layout as gemm128 (A: chunk = c*64+row).
__device__ __forceinline__ void gemm64x128(const uint16_t* __restrict__ A,
                                           const uint16_t* __restrict__ Bt,
                                           const float* __restrict__ bias,
                                           float* __restrict__ outf) {
  __shared__ uint16_t sA[2][64 * 32];
  __shared__ uint16_t sB[2][128 * 32];
  const int tid = threadIdx.x;
  const int lane = tid & 63, w = tid >> 6;
  const int l31 = lane & 31, half = lane >> 5;
  const int m0 = blockIdx.y * 64, n0 = blockIdx.x * 128;
  const int wm = (w >> 1) * 32, wn = (w & 1) * 64;

  // A: 256 chunks: ch = c*64+row (c = tid>>6 in 0..3, row = tid&63).
  const int arow_s = tid & 63, ac = tid >> 6;
  // B: 512 chunks: ch0 = tid -> (c = tid>>7, row = tid&127); ch1 -> c+2.
  const int brow_s = tid & 127, bc = tid >> 7;
  const uint16_t* a0 = A + (size_t)(m0 + arow_s) * 1024 + ac * 8;
  const uint16_t* b0 = Bt + (size_t)(n0 + brow_s) * 1024 + bc * 8;
  const uint16_t* b1 = b0 + 16;  // c+2

  gload16(a0, &sA[0][tid * 8]);
  gload16(b0, &sB[0][tid * 8]);
  gload16(b1, &sB[0][(tid + 256) * 8]);

  f32x16 acc[2] = {};

  for (int kt = 0; kt < 32; ++kt) {
    __syncthreads();
    const int cur = kt & 1;
    if (kt < 31) {
      const int ko = (kt + 1) * 32;
      const int nxt = cur ^ 1;
      gload16(a0 + ko, &sA[nxt][tid * 8]);
      gload16(b0 + ko, &sB[nxt][tid * 8]);
      gload16(b1 + ko, &sB[nxt][(tid + 256) * 8]);
    }
#pragma unroll
    for (int s = 0; s < 2; ++s) {
      const int c = s * 2 + half;
      const int arow = wm + l31;
      const bf16x8 af = *(const bf16x8*)&sA[cur][c * 512 + arow * 8];
      bf16x8 bfr[2];
#pragma unroll
      for (int j = 0; j < 2; ++j) {
        const int brow = wn + j * 32 + l31;
        bfr[j] = *(const bf16x8*)&sB[cur][c * 1024 + brow * 8];
      }
#pragma unroll
      for (int j = 0; j < 2; ++j) acc[j] = MFMA32(af, bfr[j], acc[j]);
    }
  }

#pragma unroll
  for (int j = 0; j < 2; ++j) {
    const int gn = n0 + wn + j * 32 + l31;
    const float bv = bias[gn];
#pragma unroll
    for (int reg = 0; reg < 16; ++reg) {
      const int gm = m0 + wm + (reg & 3) + 8 * (reg >> 2) + 4 * half;
      outf[(size_t)gm * 1024 + gn] = acc[j][reg] + bv;
    }
  }
}

// Q is pre-scaled by (1/sqrt(dk)) * log2(e) so attn can use exp2 directly.
#define QSCALE 0.18033688011112042f

__global__ __launch_bounds__(256) void qkv_gemm(
    const uint16_t* __restrict__ xb, const uint16_t* __restrict__ wqb,
    const uint16_t* __restrict__ wkb, const uint16_t* __restrict__ wvb,
    const float* __restrict__ bq, const float* __restrict__ bk,
    const float* __restrict__ bv, uint16_t* __restrict__ qb,
    uint16_t* __restrict__ kb, uint16_t* __restrict__ vbT) {
  // ONE static LDS allocation shared by both gemm128 instantiations (R13).
  __shared__ __align__(16) uint16_t smem[17408];  // 34 KB
  if (blockIdx.z == 0)      gemm128<0>(smem, xb, wqb, bq, QSCALE, qb);
  else if (blockIdx.z == 1) gemm128<0>(smem, xb, wkb, bk, 1.f, kb);
  else                      gemm128<2>(smem, xb, wvb, bv, 1.f, vbT);
}

__global__ __launch_bounds__(256) void o_gemm(const uint16_t* __restrict__ ab,
                                              const uint16_t* __restrict__ wob,
                                              const float* __restrict__ bo,
                                              float* __restrict__ y) {
  gemm64x128(ab, wob, bo, y);
}

// --------------------------------------------------------- flash attention
// grid (hb=32, qt=16) = 512 blocks (hb%8 -> XCD is already L2-optimal).
// 512 threads = 8 waves: rg = w&3 owns Q-cols [rg*32,+32); sh = w>>2 owns
// s-rows [sh*64,+64) of each 128-s K/V tile. 32x32x16 MFMA, S^T orientation:
//   S^T = K*Q^T  (A=K rows s, B=Q cols q)  -> C: lane=q, regs=s
//   exp2+pack   -> P^T B-operand held in REGISTERS (no LDS round-trip)
//   O^T = V^T*P^T (A=V^T rows d, B=P^T)    -> C: lane=q, regs=d
// LDS: sK/sV double-buffered, 64 KB -> 2 blocks/CU. One barrier per tile.
// Fixed-max softmax; li is per-lane; partials summed across sh at epilogue.
// Schedule = R9 per-mblk serial chain (QK,exp,PV)x2 — R10's batched variant
// measured slower. li accumulates as packed f32x2.

#define QK_CHUNK(accv, mblk_)                                               \
  do {                                                                      \
    const int srow_ = sh * 64 + (mblk_) * 32 + l31;                         \
    _Pragma("unroll") for (int s4_ = 0; s4_ < 4; ++s4_) {                   \
      const int c_ = s4_ * 2 + half;                                        \
      const bf16x8 kk_ =                                                    \
          *(const bf16x8*)&sKc[srow_ * 64 + ((c_ ^ (srow_ & 7)) << 3)];     \
      accv = MFMA32(kk_, qa[s4_], accv);                                    \
    }                                                                       \
  } while (0)

#define EXP_PACK(accv, b0_, b1_)                                            \
  do {                                                                      \
    _Pragma("unroll") for (int r_ = 0; r_ < 8; r_ += 2) {                   \
      const float pa_ = __builtin_amdgcn_exp2f(accv[r_]);                   \
      const float pb_ = __builtin_amdgcn_exp2f(accv[r_ + 1]);               \
      li2 += (f32x2){pa_, pb_};                                             \
      b0_[r_] = (__bf16)pa_;                                                \
      b0_[r_ + 1] = (__bf16)pb_;                                            \
    }                                                                       \
    _Pragma("unroll") for (int r_ = 0; r_ < 8; r_ += 2) {                   \
      const float pa_ = __builtin_amdgcn_exp2f(accv[r_ + 8]);               \
      const float pb_ = __builtin_amdgcn_exp2f(accv[r_ + 9]);               \
      li2 += (f32x2){pa_, pb_};                                             \
      b1_[r_] = (__bf16)pa_;                                                \
      b1_[r_ + 1] = (__bf16)pb_;                                            \
    }                                                                       \
  } while (0)

#define PV_CHUNK(mblk_, b0_, b1_)                                           \
  do {                                                                      \
    _Pragma("unroll") for (int t_ = 0; t_ < 2; ++t_) {                      \
      const bf16x8 bp_ = t_ ? (b1_) : (b0_);                                \
      const int cc_ = sh * 8 + (mblk_) * 4 + t_ * 2 + half;                 \
      _Pragma("unroll") for (int md_ = 0; md_ < 2; ++md_) {                 \
        const int vrow_ = md_ * 32 + l31;                                   \
        const bf16x8 vv_ =                                                  \
            *(const bf16x8*)&sVc[vrow_ * 128 + ((cc_ ^ (vrow_ & 15)) << 3)];\
        acc_o[md_] = MFMA32(vv_, bp_, acc_o[md_]);                          \
      }                                                                     \
    }                                                                       \
  } while (0)

__global__ __launch_bounds__(512, 4) void attn(const uint16_t* __restrict__ qb,
                                               const uint16_t* __restrict__ kb,
                                               const uint16_t* __restrict__ vbT,
                                               uint16_t* __restrict__ ab) {
  __shared__ __align__(16) uint16_t smem[32768];  // 64 KB
  uint16_t* sK = smem;           // [2][128*64]  32 KB  K rows s x dk
  uint16_t* sV = smem + 16384;   // [2][64*128]  32 KB  V^T rows d x s(sigma)
  const int tid = threadIdx.x;
  const int lane = tid & 63, w = tid >> 6;  // w in 0..7
  const int l31 = lane & 31, half = lane >> 5;
  const int rg = w & 3, sh = w >> 2;
  const int hb = blockIdx.x;
  const int h = hb & 15, b = hb >> 4;
  const int q0 = blockIdx.y * 128;
  const size_t qkbase = (size_t)b * 2048 * 1024 + (size_t)h * 64;
  const size_t vtbase = (size_t)hb * 64 * 2048;

  // staging: 1024 x 16B chunks per matrix per 128-s tile; 2 per thread each.
  const int ch0 = tid, ch1 = tid + 512;
  const int kr0 = ch0 >> 3, kg0 = (((ch0 & 7) ^ (kr0 & 7)) << 3);
  const int kr1 = ch1 >> 3, kg1 = (((ch1 & 7) ^ (kr1 & 7)) << 3);
  const int vr0 = ch0 >> 4, vg0 = (((ch0 & 15) ^ (vr0 & 15)) << 3);
  const int vr1 = ch1 >> 4, vg1 = (((ch1 & 15) ^ (vr1 & 15)) << 3);
  const uint16_t* k0 = kb + qkbase + (size_t)kr0 * 1024 + kg0;
  const uint16_t* k1 = kb + qkbase + (size_t)kr1 * 1024 + kg1;
  const uint16_t* v0 = vbT + vtbase + (size_t)vr0 * 2048 + vg0;
  const uint16_t* v1 = vbT + vtbase + (size_t)vr1 * 2048 + vg1;

  gload16(k0, sK + ch0 * 8);
  gload16(k1, sK + ch1 * 8);
  gload16(v0, sV + ch0 * 8);
  gload16(v1, sV + ch1 * 8);

  // Q B-frags in registers: col q = q0+rg*32+l31, k = s4*16 + half*8 + j
  bf16x8 qa[4];
  {
    const uint16_t* qrow =
        qb + qkbase + (size_t)(q0 + rg * 32 + l31) * 1024 + half * 8;
#pragma unroll
    for (int s4 = 0; s4 < 4; ++s4) qa[s4] = *(const bf16x8*)(qrow + s4 * 16);
  }

  f32x16 acc_o[2] = {};  // O^T partial: regs=d (md*32 + c-row map), lane=q
  f32x2 li2 = {0.f, 0.f};  // per-lane (q) softmax denominator, packed pair

  for (int kt = 0; kt < 16; ++kt) {
    __syncthreads();  // tile kt staged (vmcnt drain); prev-buf readers done
    const int cur = kt & 1;
    if (kt < 15) {
      const size_t soK = (size_t)(kt + 1) * 128 * 1024;
      const int soV = (kt + 1) * 128;
      const int nxt = cur ^ 1;
      gload16(k0 + soK, sK + nxt * 8192 + ch0 * 8);
      gload16(k1 + soK, sK + nxt * 8192 + ch1 * 8);
      gload16(v0 + soV, sV + nxt * 8192 + ch0 * 8);
      gload16(v1 + soV, sV + nxt * 8192 + ch1 * 8);
    }
    const uint16_t* sKc = sK + cur * 8192;
    const uint16_t* sVc = sV + cur * 8192;

#pragma unroll
    for (int mblk = 0; mblk < 2; ++mblk) {  // 32-s chunk within wave's 64 s
      f32x16 accs = {};
      QK_CHUNK(accs, mblk);
      bf16x8 bp0, bp1;
      EXP_PACK(accs, bp0, bp1);
      PV_CHUNK(mblk, bp0, bp1);
    }
  }

  float li = li2.x + li2.y;

  // epilogue: combine sh partials (pure add; fixed-max => no rescale)
  __syncthreads();  // all loop LDS reads done before reusing smem
  float* ep = (float*)smem;                  // [4][2][16][64] fp32 = 32 KB
  float* epl = (float*)(smem + 16384);       // [4][64] fp32 = 1 KB
  if (sh == 1) {
#pragma unroll
    for (int md = 0; md < 2; ++md)
#pragma unroll
      for (int reg = 0; reg < 16; ++reg)
        ep[((rg * 2 + md) * 16 + reg) * 64 + lane] = acc_o[md][reg];
    epl[rg * 64 + lane] = li;
  }
  __syncthreads();
  if (sh == 0) {
#pragma unroll
    for (int md = 0; md < 2; ++md)
#pragma unroll
      for (int reg = 0; reg < 16; ++reg)
        acc_o[md][reg] += ep[((rg * 2 + md) * 16 + reg) * 64 + lane];
    li += epl[rg * 64 + lane];
    li += __shfl_xor(li, 32);  // both halves hold the same q
    const float inv = 1.f / li;
    const int row = q0 + rg * 32 + l31;
    uint16_t* const obase = ab + (size_t)(b * 2048 + row) * 1024 + h * 64;
#pragma unroll
    for (int md = 0; md < 2; ++md)
#pragma unroll
      for (int g = 0; g < 4; ++g) {
        // regs 4g..4g+3 -> d = md*32 + 8g + 4*half + (0..3): one 8B store
        uint64_t pk = 0;
#pragma unroll
        for (int e = 0; e < 4; ++e)
          pk |= (uint64_t)f2bf(acc_o[md][g * 4 + e] * inv) << (16 * e);
        *(uint64_t*)(obase + md * 32 + g * 8 + half * 4) = pk;
      }
  }
}

// ------------------------------------------------ out = LN(x + y)*g + b
__global__ __launch_bounds__(256) void resid_ln(const float* __restrict__ x,
                                                const float* __restrict__ y,
                                                const float* __restrict__ gamma,
                                                const float* __restrict__ beta,
                                                float* __restrict__ out) {
  const int row = blockIdx.x, tid = threadIdx.x;
  const size_t base = (size_t)row * 1024 + tid * 4;
  const float4 xv = *(const float4*)(x + base);
  const float4 yv = *(const float4*)(y + base);
  const float a = xv.x + yv.x, b2 = xv.y + yv.y, c = xv.z + yv.z, d = xv.w + yv.w;
  float s = a + b2 + c + d;
#pragma unroll
  for (int o = 1; o < 64; o <<= 1) s += __shfl_xor(s, o);
  __shared__ float red[4];
  const int w = tid >> 6;
  if ((tid & 63) == 0) red[w] = s;
  __syncthreads();
  const float mu = (red[0] + red[1] + red[2] + red[3]) * (1.f / 1024.f);
  const float da = a - mu, db = b2 - mu, dc = c - mu, dd = d - mu;
  float sq = da * da + db * db + dc * dc + dd * dd;
#pragma unroll
  for (int o = 1; o < 64; o <<= 1) sq += __shfl_xor(sq, o);
  __syncthreads();
  if ((tid & 63) == 0) red[w] = sq;
  __syncthreads();
  const float var = (red[0] + red[1] + red[2] + red[3]) * (1.f / 1024.f);
  const float rs = rsqrtf(var + 1e-5f);
  const float4 g = *(const float4*)(gamma + tid * 4);
  const float4 bt = *(const float4*)(beta + tid * 4);
  float4 o4;
  o4.x = da * rs * g.x + bt.x;
  o4.y = db * rs * g.y + bt.y;
  o4.z = dc * rs * g.z + bt.z;
  o4.w = dd * rs * g.w + bt.w;
  *(float4*)(out + base) = o4;
}

// ---------------------------------------------------------------------------
extern "C" void kernel_launch(void* const* d_in, const int* in_sizes, int n_in,
                              void* d_out, int out_size, void* d_ws, size_t ws_size,
                              hipStream_t stream) {
  const float* x     = (const float*)d_in[0];
  const float* wq    = (const float*)d_in[1];
  const float* bq    = (const float*)d_in[2];
  const float* wk    = (const float*)d_in[3];
  const float* bk    = (const float*)d_in[4];
  const float* wv    = (const float*)d_in[5];
  const float* bv    = (const float*)d_in[6];
  const float* wo    = (const float*)d_in[7];
  const float* bo    = (const float*)d_in[8];
  const float* gamma = (const float*)d_in[9];
  const float* beta  = (const float*)d_in[10];
  float* out = (float*)d_out;
  char* ws = (char*)d_ws;
  const size_t MB = 1024 * 1024;
  uint16_t* xb  = (uint16_t*)(ws);            // [0,8) MB, dead after qkv_gemm
  uint16_t* ab  = xb;                         // attention out reuses xb
  uint16_t* wqb = (uint16_t*)(ws + 8 * MB);
  uint16_t* wkb = (uint16_t*)(ws + 10 * MB);
  uint16_t* wvb = (uint16_t*)(ws + 12 * MB);
  uint16_t* wob = (uint16_t*)(ws + 14 * MB);
  uint16_t* qb  = (uint16_t*)(ws + 16 * MB);  // [16,24)
  uint16_t* kb  = (uint16_t*)(ws + 24 * MB);  // [24,32)
  uint16_t* vbT = (uint16_t*)(ws + 40 * MB);  // [40,48)  (V written transposed)
  float*    y   = (float*)(ws + 16 * MB);     // [16,32) fp32, over dead qb/kb

  cvt_all<<<8192, 256, 0, stream>>>(x, wq, wk, wv, wo, xb, wqb, wkb, wvb, wob);
  qkv_gemm<<<dim3(8, 32, 3), 256, 0, stream>>>(xb, wqb, wkb, wvb, bq, bk, bv, qb, kb, vbT);
  attn<<<dim3(32, 16), 512, 0, stream>>>(qb, kb, vbT, ab);
  o_gemm<<<dim3(8, 64), 256, 0, stream>>>(ab, wob, bo, y);
  resid_ln<<<4096, 256, 0, stream>>>(x, y, gamma, beta, out);
}

// Round 6
// 196.286 us; speedup vs baseline: 1.1583x; 1.1583x over previous
//
#include <hip/hip_runtime.h>
#include <stdint.h>
#include <stddef.h>

// ---------------------------------------------------------------------------
// EinsumSelfAttention: LN(x + Attn(xWq^T+bq, xWk^T+bk, xWv^T+bv) Wo^T + bo)
// B=2 T=2048 D=1024 H=16 dk=64.  All matmuls via bf16 MFMA 32x32x16.
// Layouts: C/D (verified m74/m101): col=lane&31, row=(reg&3)+8*(reg>>2)+4*(lane>>5)
//          A/B frag: lane holds X[row/col=lane&31][k=(lane>>5)*8+j], j=0..7
// attn R9: S-TRANSPOSE trick. Compute S^T = K*Q^T (A=K, B=Q) so C has
// lane=q, regs=s. exp2+pack regs pairwise -> bf16x8 IS the B-operand of
// O^T = V^T * P^T, with V^T s-columns pre-permuted by
// sigma(j) = (j&3) + ((j>>2)&1)*8 + ((j>>3)&1)*4.
// => NO P LDS round-trip. li is a per-lane scalar.
// R10 (REVERTED): batched-QK + setprio: slower. R11: o_gemm BM=64, 512 blk.
// R12: v_trans fused into V-slice of qkv_gemm. R13: single shared 34 KB LDS
// buffer (qkv 43.4us, occ 25.9%).
// R14 (REVERTED): k-major LDS staging fixed bank conflicts (9.57M->131K)
// but qkv 43.4->61.2us, FETCH 36->58.7MB: global_load_lds lane-linearity
// turned the staging into 16B/lane @ 2048B stride (uncoalesced, 4x L2
// transactions). Conflicts at m97-parity are NOT the limiter; coalescing is.
// R15 (this round): back to R13 row-major+XOR staging, plus XCD-aware
// work-id swizzle (T1) in qkv/o gemms: the 8 blocks sharing an A-panel
// (same m-tile, all n-tiles) get equal disp%8 -> same XCD -> panel hits L2
// instead of 8x L3/HBM refetch. Targets the real R13 symptom (MfmaUtil 22.8,
// VALU 9 -> memory-latency idle at the barrier drain).
// K-loops: async-LDS double buffer via global_load_lds, one barrier per tile.
// NO register-held tile data (R5: per-thread prefetch arrays -> scratch spill).
// Measured context: dur_us includes ~2x43us harness workspace-poison fills
// (268MB each, rocprof top-5) -> controllable kernel budget ~117us.
// ---------------------------------------------------------------------------

typedef __bf16 bf16_t;
typedef bf16_t bf16x8 __attribute__((ext_vector_type(8)));
typedef float f32x16 __attribute__((ext_vector_type(16)));
typedef float f32x2 __attribute__((ext_vector_type(2)));
typedef uint16_t u16x8 __attribute__((ext_vector_type(8)));

#define MFMA32(a, b, c) __builtin_amdgcn_mfma_f32_32x32x16_bf16((a), (b), (c), 0, 0, 0)

__device__ __forceinline__ uint16_t f2bf(float f) {
  __bf16 h = (__bf16)f;
  return *(uint16_t*)&h;
}

// async global->LDS, 16B per lane. LDS dest must be wave-uniform base + lane*16.
__device__ __forceinline__ void gload16(const void* g, void* l) {
  __builtin_amdgcn_global_load_lds((const __attribute__((address_space(1))) void*)g,
                                   (__attribute__((address_space(3))) void*)l,
                                   16, 0, 0);
}

// ------------------------------------------- fp32->bf16, all 5 tensors in one
__global__ __launch_bounds__(256) void cvt_all(
    const float* __restrict__ x, const float* __restrict__ wq,
    const float* __restrict__ wk, const float* __restrict__ wv,
    const float* __restrict__ wo, uint16_t* __restrict__ xb,
    uint16_t* __restrict__ wqb, uint16_t* __restrict__ wkb,
    uint16_t* __restrict__ wvb, uint16_t* __restrict__ wob) {
  const int gid = blockIdx.x * 256 + threadIdx.x;  // 2097152 float4 chunks
  const float* src; uint16_t* dst; int off;
  if (gid < 1048576) {
    src = x; dst = xb; off = gid;
  } else {
    const int t = gid - 1048576;
    off = t & 262143;
    switch (t >> 18) {
      case 0: src = wq; dst = wqb; break;
      case 1: src = wk; dst = wkb; break;
      case 2: src = wv; dst = wvb; break;
      default: src = wo; dst = wob; break;
    }
  }
  const float4 f = ((const float4*)src)[off];
  uint64_t p = (uint64_t)f2bf(f.x) | ((uint64_t)f2bf(f.y) << 16) |
               ((uint64_t)f2bf(f.z) << 32) | ((uint64_t)f2bf(f.w) << 48);
  ((uint64_t*)dst)[off] = p;
}

// ------------------------------------------------- 128x128 GEMM, C = A*Bt^T
// BK=32, LDS double-buffered, 256 threads = 4 waves (2x2 of 64x64, each wave
// 2x2 blocks of 32x32 MFMA), one barrier per k-tile, XOR swizzle (R13 layout:
// row-major [row][32] staging, 16-row x 64B contiguous wave reads).
// smem: caller-provided 17408-elem (34 KB) buffer — shared across template
// instantiations in one kernel (R13). m0/n0 passed in (R15 XCD swizzle).
// MODE 0: bf16 row-major out.  MODE 2: V-path — epilogue transposes through
// LDS ([128 n][136 t], unioned with staging) and writes vbT (b,h,d,t) with
// the sigma s-permutation expected by attn's PV step.
template <int MODE>
__device__ __forceinline__ void gemm128(uint16_t* __restrict__ smem,
                                        const uint16_t* __restrict__ A,
                                        const uint16_t* __restrict__ Bt,
                                        const float* __restrict__ bias,
                                        float oscale,
                                        uint16_t* __restrict__ outb,
                                        int m0, int n0) {
  uint16_t* sAp = smem;          // [2][128*32] = 8192 elems
  uint16_t* sBp = smem + 8192;   // [2][128*32]
  const int tid = threadIdx.x;
  const int lane = tid & 63, w = tid >> 6;
  const int l31 = lane & 31, half = lane >> 5;
  const int wm = (w >> 1) * 64, wn = (w & 1) * 64;

  const int ch0 = tid, ch1 = tid + 256;
  const int r0 = ch0 >> 2, g0 = (((ch0 & 3) ^ (r0 & 3)) << 3);
  const int r1 = ch1 >> 2, g1 = (((ch1 & 3) ^ (r1 & 3)) << 3);
  const uint16_t* a0 = A + (size_t)(m0 + r0) * 1024 + g0;
  const uint16_t* a1 = A + (size_t)(m0 + r1) * 1024 + g1;
  const uint16_t* b0 = Bt + (size_t)(n0 + r0) * 1024 + g0;
  const uint16_t* b1 = Bt + (size_t)(n0 + r1) * 1024 + g1;

  gload16(a0, &sAp[ch0 * 8]);
  gload16(a1, &sAp[ch1 * 8]);
  gload16(b0, &sBp[ch0 * 8]);
  gload16(b1, &sBp[ch1 * 8]);

  f32x16 acc[2][2] = {};

  for (int kt = 0; kt < 32; ++kt) {
    __syncthreads();
    const int cur = kt & 1;
    if (kt < 31) {
      const int ko = (kt + 1) * 32;
      const int nxt = cur ^ 1;
      gload16(a0 + ko, &sAp[nxt * 4096 + ch0 * 8]);
      gload16(a1 + ko, &sAp[nxt * 4096 + ch1 * 8]);
      gload16(b0 + ko, &sBp[nxt * 4096 + ch0 * 8]);
      gload16(b1 + ko, &sBp[nxt * 4096 + ch1 * 8]);
    }
#pragma unroll
    for (int s = 0; s < 2; ++s) {
      const int c = s * 2 + half;
      bf16x8 af[2], bfr[2];
#pragma unroll
      for (int i = 0; i < 2; ++i) {
        const int arow = wm + i * 32 + l31;
        af[i] = *(const bf16x8*)&sAp[cur * 4096 + arow * 32 + ((c ^ (arow & 3)) << 3)];
      }
#pragma unroll
      for (int j = 0; j < 2; ++j) {
        const int brow = wn + j * 32 + l31;
        bfr[j] = *(const bf16x8*)&sBp[cur * 4096 + brow * 32 + ((c ^ (brow & 3)) << 3)];
      }
#pragma unroll
      for (int i = 0; i < 2; ++i)
#pragma unroll
        for (int j = 0; j < 2; ++j) acc[i][j] = MFMA32(af[i], bfr[j], acc[i][j]);
    }
  }

  if constexpr (MODE == 2) {
    // ---- fused v_trans epilogue ----
    __syncthreads();  // all waves done reading staging LDS
    uint16_t* vT = smem;  // [128 n][136 t]  (stride 272 B, 8B-aligned rows)
#pragma unroll
    for (int i = 0; i < 2; ++i)
#pragma unroll
      for (int j = 0; j < 2; ++j) {
        const int nl = wn + j * 32 + l31;
        const float bv = bias[n0 + nl];
#pragma unroll
        for (int g = 0; g < 4; ++g) {
          // regs 4g..4g+3 -> t = wm + i*32 + 8g + 4*half + (0..3)
          uint64_t pk = 0;
#pragma unroll
          for (int e = 0; e < 4; ++e)
            pk |= (uint64_t)f2bf(acc[i][j][g * 4 + e] + bv) << (16 * e);
          const int tl = wm + i * 32 + g * 8 + half * 4;
          *(uint64_t*)&vT[nl * 136 + tl] = pk;
        }
      }
    __syncthreads();
    // read phase: identical math to the old v_trans read loop.
    const int bb = m0 >> 11, tblk = m0 & 2047;
    const int h0 = n0 >> 6;
#pragma unroll
    for (int c = 0; c < 8; ++c) {
      const int idx = c * 256 + tid;
      const int nf = idx >> 4, t8 = (idx & 15) * 8;
      const int tb = t8 & ~15;            // 16-s block base
      const int add4 = (t8 & 8) ? 4 : 0;  // sigma for upper 8 slots
      u16x8 v;
#pragma unroll
      for (int e = 0; e < 8; ++e)
        v[e] = vT[nf * 136 + tb + ((e & 3) + ((e >> 2) << 3)) + add4];
      *(u16x8*)&outb[((size_t)(bb * 16 + h0 + (nf >> 6)) * 64 + (nf & 63)) * 2048 +
                     tblk + t8] = v;
    }
    return;
  }

#pragma unroll
  for (int i = 0; i < 2; ++i) {
#pragma unroll
    for (int j = 0; j < 2; ++j) {
      const int gn = n0 + wn + j * 32 + l31;
      const float bv = bias[gn];
#pragma unroll
      for (int reg = 0; reg < 16; ++reg) {
        const int gm = m0 + wm + i * 32 + (reg & 3) + 8 * (reg >> 2) + 4 * half;
        outb[(size_t)gm * 1024 + gn] = f2bf((acc[i][j][reg] + bv) * oscale);
      }
    }
  }
}

// ----------------------------------------- 64x128 GEMM variant for o_gemm.
// BM=64 BN=128 -> 512 blocks, 2 blocks/CU (24 KB LDS), 8 waves/CU.
// R13 row-major+XOR staging layout; m0/n0 passed in (R15 XCD swizzle).
__device__ __forceinline__ void gemm64x128(const uint16_t* __restrict__ A,
                                           const uint16_t* __restrict__ Bt,
                                           const float* __restrict__ bias,
                                           float* __restrict__ outf,
                                           int m0, int n0) {
  __shared__ uint16_t sA[2][64 * 32];
  __shared__ uint16_t sB[2][128 * 32];
  const int tid = threadIdx.x;
  const int lane = tid & 63, w = tid >> 6;
  const int l31 = lane & 31, half = lane >> 5;
  const int wm = (w >> 1) * 32, wn = (w & 1) * 64;

  // A: 64*32/8 = 256 chunks (1/thread). B: 128*32/8 = 512 chunks (2/thread).
  const int ra = tid >> 2, ga = (((tid & 3) ^ (ra & 3)) << 3);
  const int chb0 = tid, chb1 = tid + 256;
  const int rb0 = chb0 >> 2, gb0 = (((chb0 & 3) ^ (rb0 & 3)) << 3);
  const int rb1 = chb1 >> 2, gb1 = (((chb1 & 3) ^ (rb1 & 3)) << 3);
  const uint16_t* a0 = A + (size_t)(m0 + ra) * 1024 + ga;
  const uint16_t* b0 = Bt + (size_t)(n0 + rb0) * 1024 + gb0;
  const uint16_t* b1 = Bt + (size_t)(n0 + rb1) * 1024 + gb1;

  gload16(a0, &sA[0][tid * 8]);
  gload16(b0, &sB[0][chb0 * 8]);
  gload16(b1, &sB[0][chb1 * 8]);

  f32x16 acc[2] = {};

  for (int kt = 0; kt < 32; ++kt) {
    __syncthreads();
    const int cur = kt & 1;
    if (kt < 31) {
      const int ko = (kt + 1) * 32;
      const int nxt = cur ^ 1;
      gload16(a0 + ko, &sA[nxt][tid * 8]);
      gload16(b0 + ko, &sB[nxt][chb0 * 8]);
      gload16(b1 + ko, &sB[nxt][chb1 * 8]);
    }
#pragma unroll
    for (int s = 0; s < 2; ++s) {
      const int c = s * 2 + half;
      const int arow = wm + l31;
      const bf16x8 af =
          *(const bf16x8*)&sA[cur][arow * 32 + ((c ^ (arow & 3)) << 3)];
      bf16x8 bfr[2];
#pragma unroll
      for (int j = 0; j < 2; ++j) {
        const int brow = wn + j * 32 + l31;
        bfr[j] = *(const bf16x8*)&sB[cur][brow * 32 + ((c ^ (brow & 3)) << 3)];
      }
#pragma unroll
      for (int j = 0; j < 2; ++j) acc[j] = MFMA32(af, bfr[j], acc[j]);
    }
  }

#pragma unroll
  for (int j = 0; j < 2; ++j) {
    const int gn = n0 + wn + j * 32 + l31;
    const float bv = bias[gn];
#pragma unroll
    for (int reg = 0; reg < 16; ++reg) {
      const int gm = m0 + wm + (reg & 3) + 8 * (reg >> 2) + 4 * half;
      outf[(size_t)gm * 1024 + gn] = acc[j][reg] + bv;
    }
  }
}

// Q is pre-scaled by (1/sqrt(dk)) * log2(e) so attn can use exp2 directly.
#define QSCALE 0.18033688011112042f

// R15 XCD swizzle: dispatch id disp = x + 8y + 256z (x fastest); XCD ~ disp%8.
// Work decode: xw = disp/96 (n-tile), r = disp%96 -> (zw = r/32, yw = r%32).
// All 8 xw for a given r have equal disp%8 (96%8==0) -> the 8 blocks sharing
// one A-panel (m-tile yw, slice zw) land on ONE XCD -> A-panel L2-resident.
__global__ __launch_bounds__(256) void qkv_gemm(
    const uint16_t* __restrict__ xb, const uint16_t* __restrict__ wqb,
    const uint16_t* __restrict__ wkb, const uint16_t* __restrict__ wvb,
    const float* __restrict__ bq, const float* __restrict__ bk,
    const float* __restrict__ bv, uint16_t* __restrict__ qb,
    uint16_t* __restrict__ kb, uint16_t* __restrict__ vbT) {
  // ONE static LDS allocation shared by both gemm128 instantiations (R13).
  __shared__ __align__(16) uint16_t smem[17408];  // 34 KB
  const int disp = blockIdx.x + 8 * blockIdx.y + 256 * blockIdx.z;
  const int xw = disp / 96;
  const int r = disp - xw * 96;
  const int zw = r >> 5, yw = r & 31;
  const int m0 = yw * 128, n0 = xw * 128;
  if (zw == 0)      gemm128<0>(smem, xb, wqb, bq, QSCALE, qb, m0, n0);
  else if (zw == 1) gemm128<0>(smem, xb, wkb, bk, 1.f, kb, m0, n0);
  else              gemm128<2>(smem, xb, wvb, bv, 1.f, vbT, m0, n0);
}

// o_gemm: disp = x + 8y in [0,512); xw = disp/64, yw = disp%64 -> the 8
// n-tiles sharing A-panel yw land on one XCD (64%8==0).
__global__ __launch_bounds__(256) void o_gemm(const uint16_t* __restrict__ ab,
                                              const uint16_t* __restrict__ wob,
                                              const float* __restrict__ bo,
                                              float* __restrict__ y) {
  const int disp = blockIdx.x + 8 * blockIdx.y;
  const int xw = disp >> 6, yw = disp & 63;
  gemm64x128(ab, wob, bo, y, yw * 64, xw * 128);
}

// --------------------------------------------------------- flash attention
// grid (hb=32, qt=16) = 512 blocks (hb%8 -> XCD is already L2-optimal).
// 512 threads = 8 waves: rg = w&3 owns Q-cols [rg*32,+32); sh = w>>2 owns
// s-rows [sh*64,+64) of each 128-s K/V tile. 32x32x16 MFMA, S^T orientation:
//   S^T = K*Q^T  (A=K rows s, B=Q cols q)  -> C: lane=q, regs=s
//   exp2+pack   -> P^T B-operand held in REGISTERS (no LDS round-trip)
//   O^T = V^T*P^T (A=V^T rows d, B=P^T)    -> C: lane=q, regs=d
// LDS: sK/sV double-buffered, 64 KB -> 2 blocks/CU. One barrier per tile.
// Fixed-max softmax; li is per-lane; partials summed across sh at epilogue.
// Schedule = R9 per-mblk serial chain (QK,exp,PV)x2 — R10's batched variant
// measured slower. li accumulates as packed f32x2.

#define QK_CHUNK(accv, mblk_)                                               \
  do {                                                                      \
    const int srow_ = sh * 64 + (mblk_) * 32 + l31;                         \
    _Pragma("unroll") for (int s4_ = 0; s4_ < 4; ++s4_) {                   \
      const int c_ = s4_ * 2 + half;                                        \
      const bf16x8 kk_ =                                                    \
          *(const bf16x8*)&sKc[srow_ * 64 + ((c_ ^ (srow_ & 7)) << 3)];     \
      accv = MFMA32(kk_, qa[s4_], accv);                                    \
    }                                                                       \
  } while (0)

#define EXP_PACK(accv, b0_, b1_)                                            \
  do {                                                                      \
    _Pragma("unroll") for (int r_ = 0; r_ < 8; r_ += 2) {                   \
      const float pa_ = __builtin_amdgcn_exp2f(accv[r_]);                   \
      const float pb_ = __builtin_amdgcn_exp2f(accv[r_ + 1]);               \
      li2 += (f32x2){pa_, pb_};                                             \
      b0_[r_] = (__bf16)pa_;                                                \
      b0_[r_ + 1] = (__bf16)pb_;                                            \
    }                                                                       \
    _Pragma("unroll") for (int r_ = 0; r_ < 8; r_ += 2) {                   \
      const float pa_ = __builtin_amdgcn_exp2f(accv[r_ + 8]);               \
      const float pb_ = __builtin_amdgcn_exp2f(accv[r_ + 9]);               \
      li2 += (f32x2){pa_, pb_};                                             \
      b1_[r_] = (__bf16)pa_;                                                \
      b1_[r_ + 1] = (__bf16)pb_;                                            \
    }                                                                       \
  } while (0)

#define PV_CHUNK(mblk_, b0_, b1_)                                           \
  do {                                                                      \
    _Pragma("unroll") for (int t_ = 0; t_ < 2; ++t_) {                      \
      const bf16x8 bp_ = t_ ? (b1_) : (b0_);                                \
      const int cc_ = sh * 8 + (mblk_) * 4 + t_ * 2 + half;                 \
      _Pragma("unroll") for (int md_ = 0; md_ < 2; ++md_) {                 \
        const int vrow_ = md_ * 32 + l31;                                   \
        const bf16x8 vv_ =                                                  \
            *(const bf16x8*)&sVc[vrow_ * 128 + ((cc_ ^ (vrow_ & 15)) << 3)];\
        acc_o[md_] = MFMA32(vv_, bp_, acc_o[md_]);                          \
      }                                                                     \
    }                                                                       \
  } while (0)

__global__ __launch_bounds__(512, 4) void attn(const uint16_t* __restrict__ qb,
                                               const uint16_t* __restrict__ kb,
                                               const uint16_t* __restrict__ vbT,
                                               uint16_t* __restrict__ ab) {
  __shared__ __align__(16) uint16_t smem[32768];  // 64 KB
  uint16_t* sK = smem;           // [2][128*64]  32 KB  K rows s x dk
  uint16_t* sV = smem + 16384;   // [2][64*128]  32 KB  V^T rows d x s(sigma)
  const int tid = threadIdx.x;
  const int lane = tid & 63, w = tid >> 6;  // w in 0..7
  const int l31 = lane & 31, half = lane >> 5;
  const int rg = w & 3, sh = w >> 2;
  const int hb = blockIdx.x;
  const int h = hb & 15, b = hb >> 4;
  const int q0 = blockIdx.y * 128;
  const size_t qkbase = (size_t)b * 2048 * 1024 + (size_t)h * 64;
  const size_t vtbase = (size_t)hb * 64 * 2048;

  // staging: 1024 x 16B chunks per matrix per 128-s tile; 2 per thread each.
  const int ch0 = tid, ch1 = tid + 512;
  const int kr0 = ch0 >> 3, kg0 = (((ch0 & 7) ^ (kr0 & 7)) << 3);
  const int kr1 = ch1 >> 3, kg1 = (((ch1 & 7) ^ (kr1 & 7)) << 3);
  const int vr0 = ch0 >> 4, vg0 = (((ch0 & 15) ^ (vr0 & 15)) << 3);
  const int vr1 = ch1 >> 4, vg1 = (((ch1 & 15) ^ (vr1 & 15)) << 3);
  const uint16_t* k0 = kb + qkbase + (size_t)kr0 * 1024 + kg0;
  const uint16_t* k1 = kb + qkbase + (size_t)kr1 * 1024 + kg1;
  const uint16_t* v0 = vbT + vtbase + (size_t)vr0 * 2048 + vg0;
  const uint16_t* v1 = vbT + vtbase + (size_t)vr1 * 2048 + vg1;

  gload16(k0, sK + ch0 * 8);
  gload16(k1, sK + ch1 * 8);
  gload16(v0, sV + ch0 * 8);
  gload16(v1, sV + ch1 * 8);

  // Q B-frags in registers: col q = q0+rg*32+l31, k = s4*16 + half*8 + j
  bf16x8 qa[4];
  {
    const uint16_t* qrow =
        qb + qkbase + (size_t)(q0 + rg * 32 + l31) * 1024 + half * 8;
#pragma unroll
    for (int s4 = 0; s4 < 4; ++s4) qa[s4] = *(const bf16x8*)(qrow + s4 * 16);
  }

  f32x16 acc_o[2] = {};  // O^T partial: regs=d (md*32 + c-row map), lane=q
  f32x2 li2 = {0.f, 0.f};  // per-lane (q) softmax denominator, packed pair

  for (int kt = 0; kt < 16; ++kt) {
    __syncthreads();  // tile kt staged (vmcnt drain); prev-buf readers done
    const int cur = kt & 1;
    if (kt < 15) {
      const size_t soK = (size_t)(kt + 1) * 128 * 1024;
      const int soV = (kt + 1) * 128;
      const int nxt = cur ^ 1;
      gload16(k0 + soK, sK + nxt * 8192 + ch0 * 8);
      gload16(k1 + soK, sK + nxt * 8192 + ch1 * 8);
      gload16(v0 + soV, sV + nxt * 8192 + ch0 * 8);
      gload16(v1 + soV, sV + nxt * 8192 + ch1 * 8);
    }
    const uint16_t* sKc = sK + cur * 8192;
    const uint16_t* sVc = sV + cur * 8192;

#pragma unroll
    for (int mblk = 0; mblk < 2; ++mblk) {  // 32-s chunk within wave's 64 s
      f32x16 accs = {};
      QK_CHUNK(accs, mblk);
      bf16x8 bp0, bp1;
      EXP_PACK(accs, bp0, bp1);
      PV_CHUNK(mblk, bp0, bp1);
    }
  }

  float li = li2.x + li2.y;

  // epilogue: combine sh partials (pure add; fixed-max => no rescale)
  __syncthreads();  // all loop LDS reads done before reusing smem
  float* ep = (float*)smem;                  // [4][2][16][64] fp32 = 32 KB
  float* epl = (float*)(smem + 16384);       // [4][64] fp32 = 1 KB
  if (sh == 1) {
#pragma unroll
    for (int md = 0; md < 2; ++md)
#pragma unroll
      for (int reg = 0; reg < 16; ++reg)
        ep[((rg * 2 + md) * 16 + reg) * 64 + lane] = acc_o[md][reg];
    epl[rg * 64 + lane] = li;
  }
  __syncthreads();
  if (sh == 0) {
#pragma unroll
    for (int md = 0; md < 2; ++md)
#pragma unroll
      for (int reg = 0; reg < 16; ++reg)
        acc_o[md][reg] += ep[((rg * 2 + md) * 16 + reg) * 64 + lane];
    li += epl[rg * 64 + lane];
    li += __shfl_xor(li, 32);  // both halves hold the same q
    const float inv = 1.f / li;
    const int row = q0 + rg * 32 + l31;
    uint16_t* const obase = ab + (size_t)(b * 2048 + row) * 1024 + h * 64;
#pragma unroll
    for (int md = 0; md < 2; ++md)
#pragma unroll
      for (int g = 0; g < 4; ++g) {
        // regs 4g..4g+3 -> d = md*32 + 8g + 4*half + (0..3): one 8B store
        uint64_t pk = 0;
#pragma unroll
        for (int e = 0; e < 4; ++e)
          pk |= (uint64_t)f2bf(acc_o[md][g * 4 + e] * inv) << (16 * e);
        *(uint64_t*)(obase + md * 32 + g * 8 + half * 4) = pk;
      }
  }
}

// ------------------------------------------------ out = LN(x + y)*g + b
__global__ __launch_bounds__(256) void resid_ln(const float* __restrict__ x,
                                                const float* __restrict__ y,
                                                const float* __restrict__ gamma,
                                                const float* __restrict__ beta,
                                                float* __restrict__ out) {
  const int row = blockIdx.x, tid = threadIdx.x;
  const size_t base = (size_t)row * 1024 + tid * 4;
  const float4 xv = *(const float4*)(x + base);
  const float4 yv = *(const float4*)(y + base);
  const float a = xv.x + yv.x, b2 = xv.y + yv.y, c = xv.z + yv.z, d = xv.w + yv.w;
  float s = a + b2 + c + d;
#pragma unroll
  for (int o = 1; o < 64; o <<= 1) s += __shfl_xor(s, o);
  __shared__ float red[4];
  const int w = tid >> 6;
  if ((tid & 63) == 0) red[w] = s;
  __syncthreads();
  const float mu = (red[0] + red[1] + red[2] + red[3]) * (1.f / 1024.f);
  const float da = a - mu, db = b2 - mu, dc = c - mu, dd = d - mu;
  float sq = da * da + db * db + dc * dc + dd * dd;
#pragma unroll
  for (int o = 1; o < 64; o <<= 1) sq += __shfl_xor(sq, o);
  __syncthreads();
  if ((tid & 63) == 0) red[w] = sq;
  __syncthreads();
  const float var = (red[0] + red[1] + red[2] + red[3]) * (1.f / 1024.f);
  const float rs = rsqrtf(var + 1e-5f);
  const float4 g = *(const float4*)(gamma + tid * 4);
  const float4 bt = *(const float4*)(beta + tid * 4);
  float4 o4;
  o4.x = da * rs * g.x + bt.x;
  o4.y = db * rs * g.y + bt.y;
  o4.z = dc * rs * g.z + bt.z;
  o4.w = dd * rs * g.w + bt.w;
  *(float4*)(out + base) = o4;
}

// ---------------------------------------------------------------------------
extern "C" void kernel_launch(void* const* d_in, const int* in_sizes, int n_in,
                              void* d_out, int out_size, void* d_ws, size_t ws_size,
                              hipStream_t stream) {
  const float* x     = (const float*)d_in[0];
  const float* wq    = (const float*)d_in[1];
  const float* bq    = (const float*)d_in[2];
  const float* wk    = (const float*)d_in[3];
  const float* bk    = (const float*)d_in[4];
  const float* wv    = (const float*)d_in[5];
  const float* bv    = (const float*)d_in[6];
  const float* wo    = (const float*)d_in[7];
  const float* bo    = (const float*)d_in[8];
  const float* gamma = (const float*)d_in[9];
  const float* beta  = (const float*)d_in[10];
  float* out = (float*)d_out;
  char* ws = (char*)d_ws;
  const size_t MB = 1024 * 1024;
  uint16_t* xb  = (uint16_t*)(ws);            // [0,8) MB, dead after qkv_gemm
  uint16_t* ab  = xb;                         // attention out reuses xb
  uint16_t* wqb = (uint16_t*)(ws + 8 * MB);
  uint16_t* wkb = (uint16_t*)(ws + 10 * MB);
  uint16_t* wvb = (uint16_t*)(ws + 12 * MB);
  uint16_t* wob = (uint16_t*)(ws + 14 * MB);
  uint16_t* qb  = (uint16_t*)(ws + 16 * MB);  // [16,24)
  uint16_t* kb  = (uint16_t*)(ws + 24 * MB);  // [24,32)
  uint16_t* vbT = (uint16_t*)(ws + 40 * MB);  // [40,48)  (V written transposed)
  float*    y   = (float*)(ws + 16 * MB);     // [16,32) fp32, over dead qb/kb

  cvt_all<<<8192, 256, 0, stream>>>(x, wq, wk, wv, wo, xb, wqb, wkb, wvb, wob);
  qkv_gemm<<<dim3(8, 32, 3), 256, 0, stream>>>(xb, wqb, wkb, wvb, bq, bk, bv, qb, kb, vbT);
  attn<<<dim3(32, 16), 512, 0, stream>>>(qb, kb, vbT, ab);
  o_gemm<<<dim3(8, 64), 256, 0, stream>>>(ab, wob, bo, y);
  resid_ln<<<4096, 256, 0, stream>>>(x, y, gamma, beta, out);
}